// Round 2
// baseline (1125.890 us; speedup 1.0000x reference)
//
#include <hip/hip_runtime.h>

typedef unsigned short u16;
typedef unsigned int   u32;
typedef __attribute__((ext_vector_type(8))) short short8;
typedef __attribute__((ext_vector_type(4))) short short4v;
typedef __attribute__((ext_vector_type(4))) float f32x4;

#define NBATCH 16384
#define OSTR 132   // fp32 out-tile LDS stride (128+4): breaks 4-way bank conflicts, keeps 16B align

__device__ __forceinline__ u16 f2bf(float x) {
  union { float f; u32 u; } v; v.f = x;
  u32 r = v.u + 0x7FFFu + ((v.u >> 16) & 1u);
  return (u16)(r >> 16);
}
__device__ __forceinline__ float bf2f(u16 h) {
  union { u32 u; float f; } v; v.u = ((u32)h) << 16;
  return v.f;
}
// split fp32 -> (hi, lo) bf16 pair
__device__ __forceinline__ void split2(float x, u16& hi, u16& lo) {
  hi = f2bf(x);
  lo = f2bf(x - bf2f(hi));
}

// ---------- prep: transpose fp32 (M x N) -> bf16 hi/lo planes (N x M), 16 mats (layer*2+net)
__global__ __launch_bounds__(256) void split_w(
    const float* __restrict__ tsrc, const float* __restrict__ ssrc,
    u16* __restrict__ dhi, u16* __restrict__ dlo, int M, int N)
{
  __shared__ float tile[32][33];
  int z = blockIdx.z;                       // z = layer*2 + net
  const float* src = ((z & 1) ? ssrc : tsrc) + (size_t)(z >> 1) * M * N;
  size_t doff = (size_t)z * M * N;
  int n0 = blockIdx.x * 32, m0 = blockIdx.y * 32;
  for (int r = 0; r < 4; r++) {
    int m = m0 + threadIdx.y + r * 8, n = n0 + threadIdx.x;
    tile[threadIdx.y + r * 8][threadIdx.x] = src[(size_t)m * N + n];
  }
  __syncthreads();
  for (int r = 0; r < 4; r++) {
    int n = n0 + threadIdx.y + r * 8, m = m0 + threadIdx.x;
    float v = tile[threadIdx.x][threadIdx.y + r * 8];
    u16 hi, lo; split2(v, hi, lo);
    dhi[doff + (size_t)n * M + m] = hi;
    dlo[doff + (size_t)n * M + m] = lo;
  }
}

// ---------- prep: z = y, log_det = 0
__global__ __launch_bounds__(256) void prep_init(
    const float* __restrict__ y, float* __restrict__ out)
{
  int idx = blockIdx.x * 256 + threadIdx.x;
  out[idx] = y[idx];
  out[NBATCH * 64 + idx] = 0.f;
}

// ---------- prep per chunk: X = split(z[:, odd]) for layer 0
__global__ __launch_bounds__(256) void prep_x(
    const float* __restrict__ zbuf, u16* __restrict__ Xhi, u16* __restrict__ Xlo, int r0)
{
  int idx = blockIdx.x * 256 + threadIdx.x;   // mm*32 + j
  int mm = idx >> 5, j = idx & 31;
  float v = zbuf[(size_t)(r0 + mm) * 64 + 2 * j + 1];
  u16 hi, lo; split2(v, hi, lo);
  Xhi[(size_t)mm * 32 + j] = hi;
  Xlo[(size_t)mm * 32 + j] = lo;
}

// ---------- stage1: H1[CH x 1024] = relu(X[CH x 32] @ W1cat + b1cat)  (fp32 out, split GEMM)
__global__ __launch_bounds__(256) void stage1(
    const u16* __restrict__ Xhi, const u16* __restrict__ Xlo,
    const u16* __restrict__ W1hi, const u16* __restrict__ W1lo,   // [16][512][32]
    const float* __restrict__ tb1, const float* __restrict__ sb1,
    float* __restrict__ H1, int layer)
{
  __shared__ union alignas(16) {
    struct { u16 Ahi[128 * 40]; u16 Alo[128 * 40]; u16 Bhi[128 * 40]; u16 Blo[128 * 40]; } s;
    float outf[128 * OSTR];
  } sm;
  int t = threadIdx.x;
  int m0 = blockIdx.x * 128, n0 = blockIdx.y * 128;
  int net = (n0 >= 512), nn0 = n0 & 511;
  {
    const u16* ah = Xhi + (size_t)m0 * 32;
    const u16* al = Xlo + (size_t)m0 * 32;
    size_t boff = ((size_t)(layer * 2 + net) * 512 + nn0) * 32;
    const u16* bh = W1hi + boff;
    const u16* bl = W1lo + boff;
    for (int r = 0; r < 2; r++) {
      int c = r * 256 + t;            // 512 chunks of 8 elems (128 rows x 4)
      int m = c >> 2, k8 = (c & 3) * 8;
      *(uint4*)&sm.s.Ahi[m * 40 + k8] = *(const uint4*)&ah[m * 32 + k8];
      *(uint4*)&sm.s.Alo[m * 40 + k8] = *(const uint4*)&al[m * 32 + k8];
      *(uint4*)&sm.s.Bhi[m * 40 + k8] = *(const uint4*)&bh[m * 32 + k8];
      *(uint4*)&sm.s.Blo[m * 40 + k8] = *(const uint4*)&bl[m * 32 + k8];
    }
  }
  __syncthreads();
  int lane = t & 63, w = t >> 6;
  int lm = lane & 15, quad = lane >> 4;
  int roff = (w >> 1) * 64, coff = (w & 1) * 64;
  short8 ah[4], al[4], bh[4], bl[4];
#pragma unroll
  for (int tr = 0; tr < 4; tr++) {
    ah[tr] = *(const short8*)&sm.s.Ahi[(roff + tr * 16 + lm) * 40 + quad * 8];
    al[tr] = *(const short8*)&sm.s.Alo[(roff + tr * 16 + lm) * 40 + quad * 8];
  }
#pragma unroll
  for (int tc = 0; tc < 4; tc++) {
    bh[tc] = *(const short8*)&sm.s.Bhi[(coff + tc * 16 + lm) * 40 + quad * 8];
    bl[tc] = *(const short8*)&sm.s.Blo[(coff + tc * 16 + lm) * 40 + quad * 8];
  }
  f32x4 acc[4][4];
  f32x4 z4 = {0.f, 0.f, 0.f, 0.f};
#pragma unroll
  for (int tr = 0; tr < 4; tr++)
#pragma unroll
    for (int tc = 0; tc < 4; tc++) {
      f32x4 a0 = __builtin_amdgcn_mfma_f32_16x16x32_bf16(al[tr], bh[tc], z4, 0, 0, 0);
      a0 = __builtin_amdgcn_mfma_f32_16x16x32_bf16(ah[tr], bl[tc], a0, 0, 0, 0);
      acc[tr][tc] = __builtin_amdgcn_mfma_f32_16x16x32_bf16(ah[tr], bh[tc], a0, 0, 0, 0);
    }
  __syncthreads();
#pragma unroll
  for (int tc = 0; tc < 4; tc++) {
    int nloc = coff + tc * 16 + lm;
    int n = n0 + nloc;
    float bias = (n < 512) ? tb1[layer * 512 + n] : sb1[layer * 512 + n - 512];
#pragma unroll
    for (int tr = 0; tr < 4; tr++)
#pragma unroll
      for (int reg = 0; reg < 4; reg++) {
        float v = acc[tr][tc][reg] + bias;
        sm.outf[(roff + tr * 16 + quad * 4 + reg) * OSTR + nloc] = v > 0.f ? v : 0.f;
      }
  }
  __syncthreads();
  float* dst = H1 + (size_t)m0 * 1024 + n0;
  for (int it = 0; it < 16; it++) {
    int idx = it * 256 + t;           // 4096 float4
    int row = idx >> 5, c4 = (idx & 31) * 4;
    *(f32x4*)&dst[(size_t)row * 1024 + c4] = *(const f32x4*)&sm.outf[row * OSTR + c4];
  }
}

// ---------- stage2: H2 = relu(H1_net @ W2_net + b2_net), M=CH N=512 K=512, split GEMM
__global__ __launch_bounds__(256) void stage2(
    const float* __restrict__ H1, const u16* __restrict__ W2hi, const u16* __restrict__ W2lo,
    const float* __restrict__ tb2, const float* __restrict__ sb2,
    float* __restrict__ H2, int layer)
{
  __shared__ union alignas(16) {
    struct { u16 Ahi[128 * 72]; u16 Alo[128 * 72]; u16 Bhi[128 * 72]; u16 Blo[128 * 72]; } s;
    float outf[128 * OSTR];
  } sm;
  int t = threadIdx.x;
  int m0 = blockIdx.x * 128, n0 = blockIdx.y * 128, net = blockIdx.z;
  const float* Ag = H1 + (size_t)m0 * 1024 + net * 512;
  size_t boff = ((size_t)(layer * 2 + net) * 512 + n0) * 512;
  const u16* Bh = W2hi + boff;
  const u16* Bl = W2lo + boff;
  int lane = t & 63, w = t >> 6;
  int lm = lane & 15, quad = lane >> 4;
  int roff = (w >> 1) * 64, coff = (w & 1) * 64;
  f32x4 acc[4][4];
  f32x4 z4 = {0.f, 0.f, 0.f, 0.f};
#pragma unroll
  for (int tr = 0; tr < 4; tr++)
#pragma unroll
    for (int tc = 0; tc < 4; tc++) acc[tr][tc] = z4;

  for (int kk = 0; kk < 512; kk += 64) {
    __syncthreads();
    // A: 128x64 fp32 -> split to hi/lo LDS (2048 float4, 8/thread)
#pragma unroll
    for (int r = 0; r < 8; r++) {
      int idx = r * 256 + t;
      int m = idx >> 4, k4 = (idx & 15) * 4;
      f32x4 v = *(const f32x4*)&Ag[(size_t)m * 1024 + kk + k4];
      short4v hi4, lo4;
#pragma unroll
      for (int e = 0; e < 4; e++) {
        u16 h, l; split2(v[e], h, l);
        hi4[e] = (short)h; lo4[e] = (short)l;
      }
      *(short4v*)&sm.s.Ahi[m * 72 + k4] = hi4;
      *(short4v*)&sm.s.Alo[m * 72 + k4] = lo4;
    }
    // B: 128x64 bf16 hi/lo planes (1024 uint4 each, 4/thread)
#pragma unroll
    for (int r = 0; r < 4; r++) {
      int c = r * 256 + t;
      int m = c >> 3, k8 = (c & 7) * 8;
      *(uint4*)&sm.s.Bhi[m * 72 + k8] = *(const uint4*)&Bh[(size_t)m * 512 + kk + k8];
      *(uint4*)&sm.s.Blo[m * 72 + k8] = *(const uint4*)&Bl[(size_t)m * 512 + kk + k8];
    }
    __syncthreads();
#pragma unroll
    for (int kc = 0; kc < 2; kc++) {
      short8 ah[4], al[4], bh[4], bl[4];
#pragma unroll
      for (int tr = 0; tr < 4; tr++) {
        ah[tr] = *(const short8*)&sm.s.Ahi[(roff + tr * 16 + lm) * 72 + kc * 32 + quad * 8];
        al[tr] = *(const short8*)&sm.s.Alo[(roff + tr * 16 + lm) * 72 + kc * 32 + quad * 8];
      }
#pragma unroll
      for (int tc = 0; tc < 4; tc++) {
        bh[tc] = *(const short8*)&sm.s.Bhi[(coff + tc * 16 + lm) * 72 + kc * 32 + quad * 8];
        bl[tc] = *(const short8*)&sm.s.Blo[(coff + tc * 16 + lm) * 72 + kc * 32 + quad * 8];
      }
#pragma unroll
      for (int tr = 0; tr < 4; tr++)
#pragma unroll
        for (int tc = 0; tc < 4; tc++) {
          acc[tr][tc] = __builtin_amdgcn_mfma_f32_16x16x32_bf16(al[tr], bh[tc], acc[tr][tc], 0, 0, 0);
          acc[tr][tc] = __builtin_amdgcn_mfma_f32_16x16x32_bf16(ah[tr], bl[tc], acc[tr][tc], 0, 0, 0);
          acc[tr][tc] = __builtin_amdgcn_mfma_f32_16x16x32_bf16(ah[tr], bh[tc], acc[tr][tc], 0, 0, 0);
        }
    }
  }
  __syncthreads();
  const float* bias = (net ? sb2 : tb2) + layer * 512 + n0;
#pragma unroll
  for (int tc = 0; tc < 4; tc++) {
    int nloc = coff + tc * 16 + lm;
    float bv = bias[nloc];
#pragma unroll
    for (int tr = 0; tr < 4; tr++)
#pragma unroll
      for (int reg = 0; reg < 4; reg++) {
        float v = acc[tr][tc][reg] + bv;
        sm.outf[(roff + tr * 16 + quad * 4 + reg) * OSTR + nloc] = v > 0.f ? v : 0.f;
      }
  }
  __syncthreads();
  float* dst = H2 + (size_t)m0 * 1024 + net * 512 + n0;
  for (int it = 0; it < 16; it++) {
    int idx = it * 256 + t;
    int row = idx >> 5, c4 = (idx & 31) * 4;
    *(f32x4*)&dst[(size_t)row * 1024 + c4] = *(const f32x4*)&sm.outf[row * OSTR + c4];
  }
}

// ---------- stage3: t/s heads (N=32 each net) + coupling update, 64 rows/block, split GEMM
__global__ __launch_bounds__(256) void stage3(
    const float* __restrict__ H2, const u16* __restrict__ W3hi, const u16* __restrict__ W3lo,
    const float* __restrict__ tb3, const float* __restrict__ sb3,
    const float* __restrict__ s_scale, const float* __restrict__ s_shift,
    float* __restrict__ zbuf, u16* __restrict__ Xhi, u16* __restrict__ Xlo,
    int layer, int r0)
{
  __shared__ alignas(16) u16 Athi[64 * 72], Atlo[64 * 72], Ashi[64 * 72], Aslo[64 * 72];
  __shared__ alignas(16) u16 Bthi[32 * 72], Btlo[32 * 72], Bshi[32 * 72], Bslo[32 * 72];
  int t = threadIdx.x;
  int m0 = blockIdx.x * 64;
  int lane = t & 63, w = t >> 6;
  int lm = lane & 15, quad = lane >> 4;
  const float* Atg = H2 + (size_t)m0 * 1024;
  const float* Asg = Atg + 512;
  size_t bto = (size_t)(layer * 2) * 32 * 512;
  const u16* Bth = W3hi + bto; const u16* Btl = W3lo + bto;
  const u16* Bsh = Bth + 32 * 512; const u16* Bsl = Btl + 32 * 512;
  f32x4 accT[2], accS[2];
  f32x4 z4 = {0.f, 0.f, 0.f, 0.f};
  accT[0] = z4; accT[1] = z4; accS[0] = z4; accS[1] = z4;

  for (int kk = 0; kk < 512; kk += 64) {
    __syncthreads();
    // A tiles: 64x64 fp32 each net -> hi/lo (1024 float4 each, 4/thread)
#pragma unroll
    for (int r = 0; r < 4; r++) {
      int idx = r * 256 + t;
      int mm = idx >> 4, k4 = (idx & 15) * 4;
      f32x4 vt = *(const f32x4*)&Atg[(size_t)mm * 1024 + kk + k4];
      f32x4 vs = *(const f32x4*)&Asg[(size_t)mm * 1024 + kk + k4];
      short4v th, tl, sh, sl;
#pragma unroll
      for (int e = 0; e < 4; e++) {
        u16 h, l;
        split2(vt[e], h, l); th[e] = (short)h; tl[e] = (short)l;
        split2(vs[e], h, l); sh[e] = (short)h; sl[e] = (short)l;
      }
      *(short4v*)&Athi[mm * 72 + k4] = th;
      *(short4v*)&Atlo[mm * 72 + k4] = tl;
      *(short4v*)&Ashi[mm * 72 + k4] = sh;
      *(short4v*)&Aslo[mm * 72 + k4] = sl;
    }
    // B tiles: 32x64 bf16 planes (256 uint4 each, 1/thread)
    {
      int n = t >> 3, k8 = (t & 7) * 8;
      *(uint4*)&Bthi[n * 72 + k8] = *(const uint4*)&Bth[(size_t)n * 512 + kk + k8];
      *(uint4*)&Btlo[n * 72 + k8] = *(const uint4*)&Btl[(size_t)n * 512 + kk + k8];
      *(uint4*)&Bshi[n * 72 + k8] = *(const uint4*)&Bsh[(size_t)n * 512 + kk + k8];
      *(uint4*)&Bslo[n * 72 + k8] = *(const uint4*)&Bsl[(size_t)n * 512 + kk + k8];
    }
    __syncthreads();
#pragma unroll
    for (int kc = 0; kc < 2; kc++) {
      int ao = (w * 16 + lm) * 72 + kc * 32 + quad * 8;
      short8 ath = *(const short8*)&Athi[ao];
      short8 atl = *(const short8*)&Atlo[ao];
      short8 ash = *(const short8*)&Ashi[ao];
      short8 asl = *(const short8*)&Aslo[ao];
#pragma unroll
      for (int tc = 0; tc < 2; tc++) {
        int bo = (tc * 16 + lm) * 72 + kc * 32 + quad * 8;
        short8 bth = *(const short8*)&Bthi[bo];
        short8 btl = *(const short8*)&Btlo[bo];
        short8 bsh = *(const short8*)&Bshi[bo];
        short8 bsl = *(const short8*)&Bslo[bo];
        accT[tc] = __builtin_amdgcn_mfma_f32_16x16x32_bf16(atl, bth, accT[tc], 0, 0, 0);
        accT[tc] = __builtin_amdgcn_mfma_f32_16x16x32_bf16(ath, btl, accT[tc], 0, 0, 0);
        accT[tc] = __builtin_amdgcn_mfma_f32_16x16x32_bf16(ath, bth, accT[tc], 0, 0, 0);
        accS[tc] = __builtin_amdgcn_mfma_f32_16x16x32_bf16(asl, bsh, accS[tc], 0, 0, 0);
        accS[tc] = __builtin_amdgcn_mfma_f32_16x16x32_bf16(ash, bsl, accS[tc], 0, 0, 0);
        accS[tc] = __builtin_amdgcn_mfma_f32_16x16x32_bf16(ash, bsh, accS[tc], 0, 0, 0);
      }
    }
  }
  int par = layer & 1;
#pragma unroll
  for (int tc = 0; tc < 2; tc++) {
    int j = tc * 16 + lm;
    float tb = tb3[layer * 32 + j], sb = sb3[layer * 32 + j];
    float sc = s_scale[layer * 32 + j], sh = s_shift[layer * 32 + j];
#pragma unroll
    for (int reg = 0; reg < 4; reg++) {
      int m = m0 + w * 16 + quad * 4 + reg;   // local row
      float tv = accT[tc][reg] + tb;
      float sv = tanhf(accS[tc][reg] + sb) * sc + sh;
      int zc = 2 * j + par;
      size_t zi = (size_t)(r0 + m) * 64 + zc;
      float z0 = zbuf[zi];
      float zn = z0 * expf(sv) + tv;
      zbuf[zi] = zn;
      zbuf[(size_t)NBATCH * 64 + zi] += sv;
      u16 hi, lo; split2(zn, hi, lo);
      Xhi[(size_t)m * 32 + j] = hi;
      Xlo[(size_t)m * 32 + j] = lo;
    }
  }
}

extern "C" void kernel_launch(void* const* d_in, const int* in_sizes, int n_in,
                              void* d_out, int out_size, void* d_ws, size_t ws_size,
                              hipStream_t stream) {
  (void)in_sizes; (void)n_in; (void)out_size;
  const float* y   = (const float*)d_in[0];
  const float* tW1 = (const float*)d_in[1];
  const float* tb1 = (const float*)d_in[2];
  const float* tW2 = (const float*)d_in[3];
  const float* tb2 = (const float*)d_in[4];
  const float* tW3 = (const float*)d_in[5];
  const float* tb3 = (const float*)d_in[6];
  const float* sW1 = (const float*)d_in[7];
  const float* sb1 = (const float*)d_in[8];
  const float* sW2 = (const float*)d_in[9];
  const float* sb2 = (const float*)d_in[10];
  const float* sW3 = (const float*)d_in[11];
  const float* sb3 = (const float*)d_in[12];
  const float* s_scale = (const float*)d_in[13];
  const float* s_shift = (const float*)d_in[14];
  float* out = (float*)d_out;

  // fixed weight region
  char* ws = (char*)d_ws;
  const size_t W1SZ = (size_t)16 * 512 * 32 * 2;    // 524288 per plane
  const size_t W2SZ = (size_t)16 * 512 * 512 * 2;   // 8388608 per plane
  const size_t W3SZ = (size_t)16 * 32 * 512 * 2;    // 524288 per plane
  u16* W1hi = (u16*)(ws);
  u16* W1lo = (u16*)(ws + W1SZ);
  u16* W2hi = (u16*)(ws + 2 * W1SZ);
  u16* W2lo = (u16*)(ws + 2 * W1SZ + W2SZ);
  u16* W3hi = (u16*)(ws + 2 * W1SZ + 2 * W2SZ);
  u16* W3lo = (u16*)(ws + 2 * W1SZ + 2 * W2SZ + W3SZ);
  size_t fixed = 2 * W1SZ + 2 * W2SZ + 2 * W3SZ;    // 18,874,368

  // per-row chunk memory: H1 fp32 (4096) + H2 fp32 (4096) + Xhi/Xlo (128)
  const size_t PER_ROW = 8320;
  long long avail = (long long)ws_size - (long long)fixed;
  long long ch_ll = avail / (long long)PER_ROW;
  int CH = (int)(ch_ll < 128 ? 128 : ch_ll);
  CH = (CH / 128) * 128;
  if (CH > NBATCH) CH = NBATCH;

  char* dyn = ws + fixed;
  float* H1 = (float*)(dyn);
  float* H2 = (float*)(dyn + (size_t)CH * 4096);
  u16* Xhi  = (u16*)(dyn + (size_t)CH * 8192);
  u16* Xlo  = (u16*)(dyn + (size_t)CH * 8192 + (size_t)CH * 64);

  split_w<<<dim3(16, 1, 16), dim3(32, 8), 0, stream>>>(tW1, sW1, W1hi, W1lo, 32, 512);
  split_w<<<dim3(16, 16, 16), dim3(32, 8), 0, stream>>>(tW2, sW2, W2hi, W2lo, 512, 512);
  split_w<<<dim3(1, 16, 16), dim3(32, 8), 0, stream>>>(tW3, sW3, W3hi, W3lo, 512, 32);
  prep_init<<<NBATCH * 64 / 256, 256, 0, stream>>>(y, out);

  int done = 0;
  while (done < NBATCH) {
    int ch = NBATCH - done; if (ch > CH) ch = CH;
    prep_x<<<ch * 32 / 256, 256, 0, stream>>>(out, Xhi, Xlo, done);
    for (int i = 0; i < 8; i++) {
      stage1<<<dim3(ch / 128, 8), 256, 0, stream>>>(Xhi, Xlo, W1hi, W1lo, tb1, sb1, H1, i);
      stage2<<<dim3(ch / 128, 4, 2), 256, 0, stream>>>(H1, W2hi, W2lo, tb2, sb2, H2, i);
      stage3<<<dim3(ch / 64), 256, 0, stream>>>(H2, W3hi, W3lo, tb3, sb3, s_scale, s_shift,
                                                out, Xhi, Xlo, i, done);
    }
    done += ch;
  }
}

// Round 3
// 571.404 us; speedup vs baseline: 1.9704x; 1.9704x over previous
//
#include <hip/hip_runtime.h>

typedef unsigned short u16;
typedef unsigned int   u32;
typedef _Float16 f16;
typedef __attribute__((ext_vector_type(8))) _Float16 half8;
typedef __attribute__((ext_vector_type(4))) float f32x4;

#define NBATCH 16384

__device__ __forceinline__ u16 f2h(float x) {
  f16 h = (f16)x;                 // v_cvt_f16_f32, RNE
  union { f16 h; u16 u; } v; v.h = h;
  return v.u;
}

// ---------- prep: transpose fp32 (M x N) -> f16 (N x M), 16 mats (z = layer*2 + net)
__global__ __launch_bounds__(256) void cvt_w(
    const float* __restrict__ tsrc, const float* __restrict__ ssrc,
    u16* __restrict__ dst, int M, int N)
{
  __shared__ float tile[32][33];
  int z = blockIdx.z;
  const float* src = ((z & 1) ? ssrc : tsrc) + (size_t)(z >> 1) * M * N;
  u16* d = dst + (size_t)z * M * N;
  int n0 = blockIdx.x * 32, m0 = blockIdx.y * 32;
  for (int r = 0; r < 4; r++) {
    int m = m0 + threadIdx.y + r * 8, n = n0 + threadIdx.x;
    tile[threadIdx.y + r * 8][threadIdx.x] = src[(size_t)m * N + n];
  }
  __syncthreads();
  for (int r = 0; r < 4; r++) {
    int n = n0 + threadIdx.y + r * 8, m = m0 + threadIdx.x;
    d[(size_t)n * M + m] = f2h(tile[threadIdx.x][threadIdx.y + r * 8]);
  }
}

// ---------- prep: z = y, log_det = 0
__global__ __launch_bounds__(256) void prep_init(
    const float* __restrict__ y, float* __restrict__ out)
{
  int idx = blockIdx.x * 256 + threadIdx.x;
  out[idx] = y[idx];
  out[NBATCH * 64 + idx] = 0.f;
}

// ---------- prep per chunk: X = f16(z[:, odd]) for layer 0
__global__ __launch_bounds__(256) void prep_x(
    const float* __restrict__ zbuf, u16* __restrict__ X, int r0)
{
  int idx = blockIdx.x * 256 + threadIdx.x;   // mm*32 + j
  int mm = idx >> 5, j = idx & 31;
  X[(size_t)mm * 32 + j] = f2h(zbuf[(size_t)(r0 + mm) * 64 + 2 * j + 1]);
}

// ---------- stage1: H1[CH x 1024] = relu(X[CH x 32] @ W1cat + b1cat), K=32
__global__ __launch_bounds__(256, 4) void stage1(
    const u16* __restrict__ X, const u16* __restrict__ W1,   // W1: [16][512][32]
    const float* __restrict__ tb1, const float* __restrict__ sb1,
    u16* __restrict__ H1, int layer)
{
  __shared__ union alignas(16) {
    struct { u16 A[128 * 40]; u16 B[128 * 40]; } s;   // 20480 B
    u16 out[128 * 136];                               // 34816 B
  } sm;
  int t = threadIdx.x;
  int m0 = blockIdx.x * 128, n0 = blockIdx.y * 128;
  int net = (n0 >= 512), nn0 = n0 & 511;
  {
    const u16* ag = X + (size_t)m0 * 32;
    const u16* bg = W1 + ((size_t)(layer * 2 + net) * 512 + nn0) * 32;
    for (int r = 0; r < 2; r++) {
      int c = r * 256 + t;            // 512 chunks (128 rows x 4)
      int m = c >> 2, k8 = (c & 3) * 8;
      *(uint4*)&sm.s.A[m * 40 + k8] = *(const uint4*)&ag[m * 32 + k8];
      *(uint4*)&sm.s.B[m * 40 + k8] = *(const uint4*)&bg[m * 32 + k8];
    }
  }
  __syncthreads();
  int lane = t & 63, w = t >> 6;
  int lm = lane & 15, quad = lane >> 4;
  int roff = (w >> 1) * 64, coff = (w & 1) * 64;
  half8 a[4], b[4];
#pragma unroll
  for (int tr = 0; tr < 4; tr++)
    a[tr] = *(const half8*)&sm.s.A[(roff + tr * 16 + lm) * 40 + quad * 8];
#pragma unroll
  for (int tc = 0; tc < 4; tc++)
    b[tc] = *(const half8*)&sm.s.B[(coff + tc * 16 + lm) * 40 + quad * 8];
  f32x4 acc[4][4];
  f32x4 z4 = {0.f, 0.f, 0.f, 0.f};
#pragma unroll
  for (int tr = 0; tr < 4; tr++)
#pragma unroll
    for (int tc = 0; tc < 4; tc++)
      acc[tr][tc] = __builtin_amdgcn_mfma_f32_16x16x32_f16(a[tr], b[tc], z4, 0, 0, 0);
  __syncthreads();
#pragma unroll
  for (int tc = 0; tc < 4; tc++) {
    int nloc = coff + tc * 16 + lm;
    int n = n0 + nloc;
    float bias = (n < 512) ? tb1[layer * 512 + n] : sb1[layer * 512 + n - 512];
#pragma unroll
    for (int tr = 0; tr < 4; tr++)
#pragma unroll
      for (int reg = 0; reg < 4; reg++) {
        float v = acc[tr][tc][reg] + bias;
        sm.out[(roff + tr * 16 + quad * 4 + reg) * 136 + nloc] = f2h(v > 0.f ? v : 0.f);
      }
  }
  __syncthreads();
  u16* dst = H1 + (size_t)m0 * 1024 + n0;
  for (int it = 0; it < 8; it++) {
    int idx = it * 256 + t;           // 2048 uint4 (128 rows x 16)
    int row = idx >> 4, c8 = (idx & 15) * 8;
    *(uint4*)&dst[(size_t)row * 1024 + c8] = *(const uint4*)&sm.out[row * 136 + c8];
  }
}

// ---------- stage2: H2 = relu(H1_net @ W2_net + b2_net), M=CH N=512 K=512
__global__ __launch_bounds__(256, 4) void stage2(
    const u16* __restrict__ H1, const u16* __restrict__ W2,  // W2: [16][512][512]
    const float* __restrict__ tb2, const float* __restrict__ sb2,
    u16* __restrict__ H2, int layer)
{
  __shared__ union alignas(16) {
    struct { u16 A[128 * 72]; u16 B[128 * 72]; } s;   // 36864 B
    u16 out[128 * 136];                               // 34816 B
  } sm;
  int t = threadIdx.x;
  int m0 = blockIdx.x * 128, n0 = blockIdx.y * 128, net = blockIdx.z;
  const u16* Ag = H1 + (size_t)m0 * 1024 + net * 512;
  const u16* Bg = W2 + ((size_t)(layer * 2 + net) * 512 + n0) * 512;
  int lane = t & 63, w = t >> 6;
  int lm = lane & 15, quad = lane >> 4;
  int roff = (w >> 1) * 64, coff = (w & 1) * 64;
  f32x4 acc[4][4];
  f32x4 z4 = {0.f, 0.f, 0.f, 0.f};
#pragma unroll
  for (int tr = 0; tr < 4; tr++)
#pragma unroll
    for (int tc = 0; tc < 4; tc++) acc[tr][tc] = z4;

  for (int kk = 0; kk < 512; kk += 64) {
    __syncthreads();
#pragma unroll
    for (int r = 0; r < 4; r++) {
      int c = r * 256 + t;            // 1024 uint4 each (128 rows x 8)
      int m = c >> 3, k8 = (c & 7) * 8;
      *(uint4*)&sm.s.A[m * 72 + k8] = *(const uint4*)&Ag[(size_t)m * 1024 + kk + k8];
      *(uint4*)&sm.s.B[m * 72 + k8] = *(const uint4*)&Bg[(size_t)m * 512 + kk + k8];
    }
    __syncthreads();
#pragma unroll
    for (int kc = 0; kc < 2; kc++) {
      half8 a[4], b[4];
#pragma unroll
      for (int tr = 0; tr < 4; tr++)
        a[tr] = *(const half8*)&sm.s.A[(roff + tr * 16 + lm) * 72 + kc * 32 + quad * 8];
#pragma unroll
      for (int tc = 0; tc < 4; tc++)
        b[tc] = *(const half8*)&sm.s.B[(coff + tc * 16 + lm) * 72 + kc * 32 + quad * 8];
#pragma unroll
      for (int tr = 0; tr < 4; tr++)
#pragma unroll
        for (int tc = 0; tc < 4; tc++)
          acc[tr][tc] = __builtin_amdgcn_mfma_f32_16x16x32_f16(a[tr], b[tc], acc[tr][tc], 0, 0, 0);
    }
  }
  __syncthreads();
  const float* bias = (net ? sb2 : tb2) + layer * 512 + n0;
#pragma unroll
  for (int tc = 0; tc < 4; tc++) {
    int nloc = coff + tc * 16 + lm;
    float bv = bias[nloc];
#pragma unroll
    for (int tr = 0; tr < 4; tr++)
#pragma unroll
      for (int reg = 0; reg < 4; reg++) {
        float v = acc[tr][tc][reg] + bv;
        sm.out[(roff + tr * 16 + quad * 4 + reg) * 136 + nloc] = f2h(v > 0.f ? v : 0.f);
      }
  }
  __syncthreads();
  u16* dst = H2 + (size_t)m0 * 1024 + net * 512 + n0;
  for (int it = 0; it < 8; it++) {
    int idx = it * 256 + t;
    int row = idx >> 4, c8 = (idx & 15) * 8;
    *(uint4*)&dst[(size_t)row * 1024 + c8] = *(const uint4*)&sm.out[row * 136 + c8];
  }
}

// ---------- stage3: t/s heads (N=32 each net) + coupling update, 64 rows/block
__global__ __launch_bounds__(256, 4) void stage3(
    const u16* __restrict__ H2, const u16* __restrict__ W3,  // W3: [16][32][512]
    const float* __restrict__ tb3, const float* __restrict__ sb3,
    const float* __restrict__ s_scale, const float* __restrict__ s_shift,
    float* __restrict__ zbuf, u16* __restrict__ X, int layer, int r0)
{
  __shared__ alignas(16) u16 At[64 * 72], As[64 * 72];
  __shared__ alignas(16) u16 Bt[32 * 72], Bs[32 * 72];
  int t = threadIdx.x;
  int m0 = blockIdx.x * 64;
  int lane = t & 63, w = t >> 6;
  int lm = lane & 15, quad = lane >> 4;
  const u16* Atg = H2 + (size_t)m0 * 1024;
  const u16* Asg = Atg + 512;
  const u16* Btg = W3 + (size_t)(layer * 2) * 32 * 512;
  const u16* Bsg = Btg + 32 * 512;
  f32x4 accT[2], accS[2];
  f32x4 z4 = {0.f, 0.f, 0.f, 0.f};
  accT[0] = z4; accT[1] = z4; accS[0] = z4; accS[1] = z4;

  for (int kk = 0; kk < 512; kk += 64) {
    __syncthreads();
#pragma unroll
    for (int r = 0; r < 2; r++) {
      int c = r * 256 + t;            // 512 uint4 each (64 rows x 8)
      int m = c >> 3, k8 = (c & 7) * 8;
      *(uint4*)&At[m * 72 + k8] = *(const uint4*)&Atg[(size_t)m * 1024 + kk + k8];
      *(uint4*)&As[m * 72 + k8] = *(const uint4*)&Asg[(size_t)m * 1024 + kk + k8];
    }
    {
      int n = t >> 3, k8 = (t & 7) * 8;  // 256 uint4 (32 rows x 8)
      *(uint4*)&Bt[n * 72 + k8] = *(const uint4*)&Btg[(size_t)n * 512 + kk + k8];
      *(uint4*)&Bs[n * 72 + k8] = *(const uint4*)&Bsg[(size_t)n * 512 + kk + k8];
    }
    __syncthreads();
#pragma unroll
    for (int kc = 0; kc < 2; kc++) {
      int ao = (w * 16 + lm) * 72 + kc * 32 + quad * 8;
      half8 a_t = *(const half8*)&At[ao];
      half8 a_s = *(const half8*)&As[ao];
#pragma unroll
      for (int tc = 0; tc < 2; tc++) {
        int bo = (tc * 16 + lm) * 72 + kc * 32 + quad * 8;
        half8 b_t = *(const half8*)&Bt[bo];
        half8 b_s = *(const half8*)&Bs[bo];
        accT[tc] = __builtin_amdgcn_mfma_f32_16x16x32_f16(a_t, b_t, accT[tc], 0, 0, 0);
        accS[tc] = __builtin_amdgcn_mfma_f32_16x16x32_f16(a_s, b_s, accS[tc], 0, 0, 0);
      }
    }
  }
  int par = layer & 1;
#pragma unroll
  for (int tc = 0; tc < 2; tc++) {
    int j = tc * 16 + lm;
    float tb = tb3[layer * 32 + j], sb = sb3[layer * 32 + j];
    float sc = s_scale[layer * 32 + j], sh = s_shift[layer * 32 + j];
#pragma unroll
    for (int reg = 0; reg < 4; reg++) {
      int m = m0 + w * 16 + quad * 4 + reg;   // local row
      float tv = accT[tc][reg] + tb;
      float sv = tanhf(accS[tc][reg] + sb) * sc + sh;
      int zc = 2 * j + par;
      size_t zi = (size_t)(r0 + m) * 64 + zc;
      float z0 = zbuf[zi];
      float zn = z0 * expf(sv) + tv;
      zbuf[zi] = zn;
      zbuf[(size_t)NBATCH * 64 + zi] += sv;
      X[(size_t)m * 32 + j] = f2h(zn);
    }
  }
}

extern "C" void kernel_launch(void* const* d_in, const int* in_sizes, int n_in,
                              void* d_out, int out_size, void* d_ws, size_t ws_size,
                              hipStream_t stream) {
  (void)in_sizes; (void)n_in; (void)out_size;
  const float* y   = (const float*)d_in[0];
  const float* tW1 = (const float*)d_in[1];
  const float* tb1 = (const float*)d_in[2];
  const float* tW2 = (const float*)d_in[3];
  const float* tb2 = (const float*)d_in[4];
  const float* tW3 = (const float*)d_in[5];
  const float* tb3 = (const float*)d_in[6];
  const float* sW1 = (const float*)d_in[7];
  const float* sb1 = (const float*)d_in[8];
  const float* sW2 = (const float*)d_in[9];
  const float* sb2 = (const float*)d_in[10];
  const float* sW3 = (const float*)d_in[11];
  const float* sb3 = (const float*)d_in[12];
  const float* s_scale = (const float*)d_in[13];
  const float* s_shift = (const float*)d_in[14];
  float* out = (float*)d_out;

  // fixed weight region (f16 single-plane)
  char* ws = (char*)d_ws;
  const size_t W1SZ = (size_t)16 * 512 * 32 * 2;    // 524288
  const size_t W2SZ = (size_t)16 * 512 * 512 * 2;   // 8388608
  const size_t W3SZ = (size_t)16 * 32 * 512 * 2;    // 524288
  u16* W1 = (u16*)(ws);
  u16* W2 = (u16*)(ws + W1SZ);
  u16* W3 = (u16*)(ws + W1SZ + W2SZ);
  size_t fixed = W1SZ + W2SZ + W3SZ;                // 9,437,184

  // per-row chunk memory: H1 f16 (2048 B) + H2 f16 (2048 B) + X f16 (64 B)
  const size_t PER_ROW = 4160;
  long long avail = (long long)ws_size - (long long)fixed;
  long long ch_ll = avail / (long long)PER_ROW;
  int CH = (int)(ch_ll < 128 ? 128 : ch_ll);
  CH = (CH / 128) * 128;
  if (CH > NBATCH) CH = NBATCH;

  char* dyn = ws + fixed;
  u16* H1 = (u16*)(dyn);
  u16* H2 = (u16*)(dyn + (size_t)CH * 2048);
  u16* X  = (u16*)(dyn + (size_t)CH * 4096);

  cvt_w<<<dim3(16, 1, 16), dim3(32, 8), 0, stream>>>(tW1, sW1, W1, 32, 512);
  cvt_w<<<dim3(16, 16, 16), dim3(32, 8), 0, stream>>>(tW2, sW2, W2, 512, 512);
  cvt_w<<<dim3(1, 16, 16), dim3(32, 8), 0, stream>>>(tW3, sW3, W3, 512, 32);
  prep_init<<<NBATCH * 64 / 256, 256, 0, stream>>>(y, out);

  int done = 0;
  while (done < NBATCH) {
    int ch = NBATCH - done; if (ch > CH) ch = CH;
    prep_x<<<ch * 32 / 256, 256, 0, stream>>>(out, X, done);
    for (int i = 0; i < 8; i++) {
      stage1<<<dim3(ch / 128, 8), 256, 0, stream>>>(X, W1, tb1, sb1, H1, i);
      stage2<<<dim3(ch / 128, 4, 2), 256, 0, stream>>>(H1, W2, tb2, sb2, H2, i);
      stage3<<<dim3(ch / 64), 256, 0, stream>>>(H2, W3, tb3, sb3, s_scale, s_shift,
                                                out, X, i, done);
    }
    done += ch;
  }
}

// Round 4
// 550.399 us; speedup vs baseline: 2.0456x; 1.0382x over previous
//
#include <hip/hip_runtime.h>

typedef unsigned short u16;
typedef unsigned int   u32;
typedef _Float16 f16;
typedef __attribute__((ext_vector_type(8))) _Float16 half8;
typedef __attribute__((ext_vector_type(4))) float f32x4;

#define NBATCH 16384

__device__ __forceinline__ u16 f2h(float x) {
  union { f16 h; u16 u; } v; v.h = (f16)x; return v.u;
}

// ---------- prep: transpose fp32 (M x N) -> f16 (N x M), 16 mats (z = layer*2 + net)
__global__ __launch_bounds__(256) void cvt_w(
    const float* __restrict__ tsrc, const float* __restrict__ ssrc,
    u16* __restrict__ dst, int M, int N)
{
  __shared__ float tile[32][33];
  int z = blockIdx.z;
  const float* src = ((z & 1) ? ssrc : tsrc) + (size_t)(z >> 1) * M * N;
  u16* d = dst + (size_t)z * M * N;
  int n0 = blockIdx.x * 32, m0 = blockIdx.y * 32;
  for (int r = 0; r < 4; r++) {
    int m = m0 + threadIdx.y + r * 8, n = n0 + threadIdx.x;
    tile[threadIdx.y + r * 8][threadIdx.x] = src[(size_t)m * N + n];
  }
  __syncthreads();
  for (int r = 0; r < 4; r++) {
    int n = n0 + threadIdx.y + r * 8, m = m0 + threadIdx.x;
    d[(size_t)n * M + m] = f2h(tile[threadIdx.x][threadIdx.y + r * 8]);
  }
}

// ---------- fused RealNVP: 1 block = 64 batch rows, all 8 layers internally.
// LDS: reg1/reg2 = 64x512 f16, XOR-swizzled k-chunks (chunk c at c^(m&7)).
// z, log_det live in registers: thread t owns row (t>>2), cols [(t&3)*16, +16).
__global__ __launch_bounds__(256, 1) void meganvp(
    const float* __restrict__ y,
    const u16* __restrict__ W1T, const u16* __restrict__ W2T, const u16* __restrict__ W3T,
    const float* __restrict__ tb1, const float* __restrict__ sb1,
    const float* __restrict__ tb2, const float* __restrict__ sb2,
    const float* __restrict__ tb3, const float* __restrict__ sb3,
    const float* __restrict__ s_scale, const float* __restrict__ s_shift,
    float* __restrict__ out)
{
  __shared__ u16 reg1[64 * 512];   // 64 KB: H1 (per net); TS pair buffer at coupling
  __shared__ u16 reg2[64 * 512];   // 64 KB: X (first 2560 elems) then H2 (per net)

  const int t = threadIdx.x;
  const int m0 = blockIdx.x * 64;
  const int lane = t & 63, w = t >> 6, lm = lane & 15, quad = lane >> 4;
  const int phase = blockIdx.x & 15;
  const int zr = t >> 2, zq = t & 3, c0 = zq * 16;
  const int cw = w * 128;                       // wave's 128-col slice of the 512 features

  float z[16], ld[16];
  {
    const float* yb = y + (size_t)(m0 + zr) * 64 + c0;
#pragma unroll
    for (int e = 0; e < 4; e++) {
      f32x4 v = *(const f32x4*)&yb[e * 4];
#pragma unroll
      for (int k = 0; k < 4; k++) z[e * 4 + k] = v[k];
    }
#pragma unroll
    for (int e = 0; e < 16; e++) ld[e] = 0.f;
  }

  f32x4 hT[2], hS[2];

  for (int layer = 0; layer < 8; layer++) {
    const int par = layer & 1;
    for (int net = 0; net < 2; net++) {
      const int idx = layer * 2 + net;
      __syncthreads();                           // reg2 free (head / prev-layer reads done)
      { // build X[64][40] from pass-through z half: one b128 per thread
        union { u16 a[8]; uint4 v; } xv;
#pragma unroll
        for (int e = 0; e < 8; e++) xv.a[e] = f2h(z[2 * e + 1 - par]);
        *(uint4*)&reg2[zr * 40 + zq * 8] = xv.v;
      }
      __syncthreads();

      // ---- H1 = relu(X @ W1 + b1): K=32 (single MFMA step), out cols [cw, cw+128)
      {
        const float* B1 = (net ? sb1 : tb1) + layer * 512 + cw + lm;
        float bias1[8];
#pragma unroll
        for (int ct = 0; ct < 8; ct++) bias1[ct] = B1[ct * 16];
        const u16* W1p = W1T + ((size_t)idx * 512 + cw + lm) * 32 + quad * 8;
        half8 bv[8];
#pragma unroll
        for (int ct = 0; ct < 8; ct++) bv[ct] = *(const half8*)&W1p[ct * 512];
        half8 av[4];
#pragma unroll
        for (int rt = 0; rt < 4; rt++)
          av[rt] = *(const half8*)&reg2[(rt * 16 + lm) * 40 + quad * 8];
        f32x4 zz = {0.f, 0.f, 0.f, 0.f};
        f32x4 acc1[4][8];
#pragma unroll
        for (int rt = 0; rt < 4; rt++)
#pragma unroll
          for (int ct = 0; ct < 8; ct++)
            acc1[rt][ct] = __builtin_amdgcn_mfma_f32_16x16x32_f16(av[rt], bv[ct], zz, 0, 0, 0);
        // epilogue -> reg1 (swizzled scalar b16 writes)
#pragma unroll
        for (int rt = 0; rt < 4; rt++) {
          const int mrow = rt * 16 + quad * 4;
#pragma unroll
          for (int ct = 0; ct < 8; ct++) {
            const int n = cw + ct * 16 + lm;
#pragma unroll
            for (int r = 0; r < 4; r++) {
              float v = acc1[rt][ct][r] + bias1[ct];
              v = v > 0.f ? v : 0.f;
              const int m = mrow + r;
              reg1[m * 512 + ((((n >> 3) ^ (m & 7)) << 3) | (n & 7))] = f2h(v);
            }
          }
        }
      }
      __syncthreads();

      // ---- H2 = relu(H1 @ W2 + b2): K=512, B streamed global->VGPR, prefetch depth 2
      {
        const float* B2 = (net ? sb2 : tb2) + layer * 512 + cw + lm;
        float bias2[8];
#pragma unroll
        for (int ct = 0; ct < 8; ct++) bias2[ct] = B2[ct * 16];
        const u16* W2p = W2T + ((size_t)idx * 512 + cw + lm) * 512 + quad * 8;
        f32x4 zz = {0.f, 0.f, 0.f, 0.f};
        f32x4 acc[4][8];
#pragma unroll
        for (int rt = 0; rt < 4; rt++)
#pragma unroll
          for (int ct = 0; ct < 8; ct++) acc[rt][ct] = zz;
        half8 bb[2][8];
        {
          const int kk0 = (phase & 15) * 32, kk1 = ((phase + 1) & 15) * 32;
#pragma unroll
          for (int ct = 0; ct < 8; ct++) {
            bb[0][ct] = *(const half8*)&W2p[ct * 8192 + kk0];
            bb[1][ct] = *(const half8*)&W2p[ct * 8192 + kk1];
          }
        }
#pragma unroll
        for (int ci = 0; ci < 16; ci++) {
          const int kk = ((ci + phase) & 15) * 32;
          half8 av[4];
#pragma unroll
          for (int rt = 0; rt < 4; rt++) {
            const int m = rt * 16 + lm;
            av[rt] = *(const half8*)&reg1[m * 512 + ((((kk >> 3) + quad) ^ (m & 7)) << 3)];
          }
          half8 cur[8];
#pragma unroll
          for (int ct = 0; ct < 8; ct++) cur[ct] = bb[ci & 1][ct];
          if (ci < 14) {
            const int kn = ((ci + 2 + phase) & 15) * 32;
#pragma unroll
            for (int ct = 0; ct < 8; ct++)
              bb[ci & 1][ct] = *(const half8*)&W2p[ct * 8192 + kn];
          }
#pragma unroll
          for (int rt = 0; rt < 4; rt++)
#pragma unroll
            for (int ct = 0; ct < 8; ct++)
              acc[rt][ct] = __builtin_amdgcn_mfma_f32_16x16x32_f16(av[rt], cur[ct], acc[rt][ct], 0, 0, 0);
        }
        // epilogue -> reg2 (X region dead: all X reads completed before H1-epilogue barrier)
#pragma unroll
        for (int rt = 0; rt < 4; rt++) {
          const int mrow = rt * 16 + quad * 4;
#pragma unroll
          for (int ct = 0; ct < 8; ct++) {
            const int n = cw + ct * 16 + lm;
#pragma unroll
            for (int r = 0; r < 4; r++) {
              float v = acc[rt][ct][r] + bias2[ct];
              v = v > 0.f ? v : 0.f;
              const int m = mrow + r;
              reg2[m * 512 + ((((n >> 3) ^ (m & 7)) << 3) | (n & 7))] = f2h(v);
            }
          }
        }
      }
      __syncthreads();

      // ---- head: out 16 rows (w*16..) x 32 cols, K=512
      {
        const u16* W3p = W3T + ((size_t)idx * 32 + lm) * 512 + quad * 8;
        f32x4 ha[2];
        ha[0] = (f32x4){0.f, 0.f, 0.f, 0.f}; ha[1] = ha[0];
        const int m = w * 16 + lm;
#pragma unroll
        for (int ci = 0; ci < 16; ci++) {
          const int kk = ((ci + phase) & 15) * 32;
          half8 av = *(const half8*)&reg2[m * 512 + ((((kk >> 3) + quad) ^ (m & 7)) << 3)];
          half8 b0 = *(const half8*)&W3p[kk];
          half8 b1 = *(const half8*)&W3p[8192 + kk];
          ha[0] = __builtin_amdgcn_mfma_f32_16x16x32_f16(av, b0, ha[0], 0, 0, 0);
          ha[1] = __builtin_amdgcn_mfma_f32_16x16x32_f16(av, b1, ha[1], 0, 0, 0);
        }
        if (net == 0) {
#pragma unroll
          for (int ct = 0; ct < 2; ct++) {
            const float b3 = tb3[layer * 32 + ct * 16 + lm];
#pragma unroll
            for (int r = 0; r < 4; r++) hT[ct][r] = ha[ct][r] + b3;
          }
        } else {
#pragma unroll
          for (int ct = 0; ct < 2; ct++) {
            const int j = layer * 32 + ct * 16 + lm;
            const float b3 = sb3[j], sc = s_scale[j], sh = s_shift[j];
#pragma unroll
            for (int r = 0; r < 4; r++) hS[ct][r] = tanhf(ha[ct][r] + b3) * sc + sh;
          }
        }
      }
    } // net

    // ---- coupling: route (t,s) pairs through reg1 (fp32, row stride 68 floats)
    {
      float* TS = (float*)reg1;     // reg1 reads (H2 a-reads) fenced by pre-head barrier
#pragma unroll
      for (int ct = 0; ct < 2; ct++) {
#pragma unroll
        for (int r = 0; r < 4; r++) {
          const int m = w * 16 + quad * 4 + r, j = ct * 16 + lm;
          float2 p; p.x = hT[ct][r]; p.y = hS[ct][r];
          *(float2*)&TS[m * 68 + 2 * j] = p;
        }
      }
      __syncthreads();
      const float* base = &TS[zr * 68 + zq * 16];
      float q[16];
#pragma unroll
      for (int e = 0; e < 4; e++) {
        f32x4 v = *(const f32x4*)&base[e * 4];
#pragma unroll
        for (int k = 0; k < 4; k++) q[e * 4 + k] = v[k];
      }
#pragma unroll
      for (int e = 0; e < 8; e++) {
        const float tv = q[2 * e], sv = q[2 * e + 1];
        const int zl = 2 * e + par;
        z[zl] = z[zl] * expf(sv) + tv;
        ld[zl] += sv;
      }
    }
  } // layer

  // ---- store z and log_det
  {
    float* zb = out + (size_t)(m0 + zr) * 64 + c0;
    float* lb = out + (size_t)NBATCH * 64 + (size_t)(m0 + zr) * 64 + c0;
#pragma unroll
    for (int e = 0; e < 4; e++) {
      f32x4 v, l;
#pragma unroll
      for (int k = 0; k < 4; k++) { v[k] = z[e * 4 + k]; l[k] = ld[e * 4 + k]; }
      *(f32x4*)&zb[e * 4] = v;
      *(f32x4*)&lb[e * 4] = l;
    }
  }
}

extern "C" void kernel_launch(void* const* d_in, const int* in_sizes, int n_in,
                              void* d_out, int out_size, void* d_ws, size_t ws_size,
                              hipStream_t stream) {
  (void)in_sizes; (void)n_in; (void)out_size; (void)ws_size;
  const float* y   = (const float*)d_in[0];
  const float* tW1 = (const float*)d_in[1];
  const float* tb1 = (const float*)d_in[2];
  const float* tW2 = (const float*)d_in[3];
  const float* tb2 = (const float*)d_in[4];
  const float* tW3 = (const float*)d_in[5];
  const float* tb3 = (const float*)d_in[6];
  const float* sW1 = (const float*)d_in[7];
  const float* sb1 = (const float*)d_in[8];
  const float* sW2 = (const float*)d_in[9];
  const float* sb2 = (const float*)d_in[10];
  const float* sW3 = (const float*)d_in[11];
  const float* sb3 = (const float*)d_in[12];
  const float* s_scale = (const float*)d_in[13];
  const float* s_shift = (const float*)d_in[14];
  float* out = (float*)d_out;

  char* ws = (char*)d_ws;
  const size_t W1SZ = (size_t)16 * 512 * 32 * 2;    // 524288
  const size_t W2SZ = (size_t)16 * 512 * 512 * 2;   // 8388608
  u16* W1 = (u16*)(ws);
  u16* W2 = (u16*)(ws + W1SZ);
  u16* W3 = (u16*)(ws + W1SZ + W2SZ);

  cvt_w<<<dim3(16, 1, 16), dim3(32, 8), 0, stream>>>(tW1, sW1, W1, 32, 512);
  cvt_w<<<dim3(16, 16, 16), dim3(32, 8), 0, stream>>>(tW2, sW2, W2, 512, 512);
  cvt_w<<<dim3(1, 16, 16), dim3(32, 8), 0, stream>>>(tW3, sW3, W3, 512, 32);

  meganvp<<<256, 256, 0, stream>>>(y, W1, W2, W3, tb1, sb1, tb2, sb2, tb3, sb3,
                                   s_scale, s_shift, out);
}